// Round 1
// baseline (601.427 us; speedup 1.0000x reference)
//
#include <hip/hip_runtime.h>
#include <hip/hip_bf16.h>
#include <cstdint>

#define T_TOK 16384   // B*S = 8*2048
#define D     512
#define E     8

// ---------------------------------------------------------------------------
// W1 transpose: WT[d][f] = W[f][d]  (so layer-1 GEMM uses the same NN core)
// ---------------------------------------------------------------------------
__global__ __launch_bounds__(256) void k_transpose(const float* __restrict__ W,
                                                   float* __restrict__ WT)
{
    __shared__ float tile[32][33];
    const int bx = blockIdx.x << 5;   // source col (d)
    const int by = blockIdx.y << 5;   // source row (f)
    const int tx = threadIdx.x & 31;
    const int ty = threadIdx.x >> 5;  // 0..7
#pragma unroll
    for (int i = 0; i < 32; i += 8)
        tile[ty + i][tx] = W[(size_t)(by + ty + i) * D + bx + tx];
    __syncthreads();
#pragma unroll
    for (int i = 0; i < 32; i += 8)
        WT[(size_t)(bx + ty + i) * D + by + tx] = tile[tx][ty + i];
}

// ---------------------------------------------------------------------------
// zero the small state (counts, embed) — ws is poisoned 0xAA every call
// ---------------------------------------------------------------------------
__global__ void k_zero(int* c2, int* c3, float* embed)
{
    const int tid = threadIdx.x;
    if (tid < E) { c2[tid] = 0; c3[tid] = 0; }
    for (int i = tid; i < 8 * D; i += 256) embed[i] = 0.f;
}

// ---------------------------------------------------------------------------
// Gating: logits = H @ gw  -> top-1 expert, gate prob; bucket tokens by expert
// grid 64 x 256 threads = one thread per token
// ---------------------------------------------------------------------------
__global__ __launch_bounds__(256) void k_gating(const float* __restrict__ H,
                                                const float* __restrict__ gw,
                                                float* __restrict__ p,
                                                int* __restrict__ lists,
                                                int* __restrict__ counts)
{
    __shared__ float gws[D * E];   // 16 KB
    const int tid = threadIdx.x;
    for (int i = tid; i < D * E; i += 256) gws[i] = gw[i];
    __syncthreads();

    const int t = blockIdx.x * 256 + tid;
    const float* hrow = H + (size_t)t * D;
    float acc[E];
#pragma unroll
    for (int e = 0; e < E; ++e) acc[e] = 0.f;

    for (int d = 0; d < D; d += 4) {
        const float4 hv = *(const float4*)(hrow + d);
#pragma unroll
        for (int e = 0; e < E; ++e)
            acc[e] += hv.x * gws[(d + 0) * E + e] + hv.y * gws[(d + 1) * E + e]
                    + hv.z * gws[(d + 2) * E + e] + hv.w * gws[(d + 3) * E + e];
    }

    float m = acc[0]; int mi = 0;
#pragma unroll
    for (int e = 1; e < E; ++e)
        if (acc[e] > m) { m = acc[e]; mi = e; }   // strict > == jnp.argmax first-max
    float ssum = 0.f;
#pragma unroll
    for (int e = 0; e < E; ++e) ssum += expf(acc[e] - m);
    p[t] = 1.0f / ssum;   // == max(softmax(logits))

    // wave-aggregated bucket insert: 8 atomics per wave instead of 64
    const int lane = tid & 63;
    const unsigned long long below = (lane == 0) ? 0ULL : ((~0ULL) >> (64 - lane));
#pragma unroll 1
    for (int e = 0; e < E; ++e) {
        const unsigned long long mask = __ballot(mi == e);
        if (mi == e) {
            const int leader = __ffsll((unsigned long long)mask) - 1;
            int base = 0;
            if (lane == leader) base = atomicAdd(&counts[e], (int)__popcll(mask));
            base = __shfl(base, leader);
            const int offs = (int)__popcll(mask & below);
            lists[e * T_TOK + base + offs] = t;
        }
    }
}

// ---------------------------------------------------------------------------
// Build M-tile descriptors from per-expert counts (<=135 tiles of 128 tokens)
// ---------------------------------------------------------------------------
__global__ void k_desc(const int* __restrict__ counts, int4* __restrict__ desc,
                       int* __restrict__ ntiles)
{
    if (threadIdx.x == 0) {
        int total = 0;
        for (int e = 0; e < E; ++e) {
            const int c = counts[e];
            for (int m = 0; m < c; m += 128) {
                desc[total++] = make_int4(e, e * T_TOK + m, min(128, c - m), 0);
            }
        }
        *ntiles = total;
    }
}

// ---------------------------------------------------------------------------
// Unified fp32 GEMM, 128x128 tile, BK=16, 256 threads, 8x8 microtile.
//   GATHER=false: C[t] = A[t] @ B + bias                (layer-1 linear)
//   GATHER=true : C[t] = (A[t] @ We[e] + be[e]) * p[t]  (grouped expert GEMM)
// LDS layout k-major: As[k][m], Bs[k][n] -> all fragment reads are b128,
// conflict-free; staging writes are <=2-way (free).
// ---------------------------------------------------------------------------
template <bool GATHER>
__global__ __launch_bounds__(256) void k_gemm(const float* __restrict__ A,
                                              const float* __restrict__ B,
                                              const float* __restrict__ bias,
                                              const float* __restrict__ scale,
                                              const int* __restrict__ lists,
                                              const int4* __restrict__ desc,
                                              const int* __restrict__ ntiles,
                                              float* __restrict__ C)
{
    __shared__ float As[16][128];
    __shared__ float Bs[16][128];
    __shared__ int Ts[128];

    const int tid = threadIdx.x;
    const int mt = blockIdx.x;
    const float* Bb;
    const float* bb;
    int mcnt, listoff = 0;
    if constexpr (GATHER) {
        if (mt >= *ntiles) return;
        const int4 dsc = desc[mt];
        const int e = dsc.x;
        listoff = dsc.y;
        mcnt = dsc.z;
        Bb = B + ((size_t)e << 18);      // e * 512*512
        bb = bias + (e << 9);            // e * 512
    } else {
        Bb = B; bb = bias; mcnt = 128;
    }
    const int n0 = blockIdx.y << 7;

    if (tid < 128) {
        int t;
        if constexpr (GATHER) t = (tid < mcnt) ? lists[listoff + tid] : -1;
        else                  t = (mt << 7) + tid;
        Ts[tid] = t;
    }
    __syncthreads();

    // staging assignment: one A-row half (8 floats) + one B-row chunk per thread
    const int m_s = tid >> 1;                 // A row within tile (0..127)
    const int ka  = (tid & 1) << 3;           // k offset 0 or 8
    const int kb  = tid >> 4;                 // B row (0..15)
    const int nbq = (tid & 15) << 2;          // B col offset (dwords), +64 for 2nd
    const int tA  = Ts[m_s];
    const bool valid = (tA >= 0);
    const float* Ap = A + (size_t)(valid ? tA : 0) * D + ka;
    const float* Bp = Bb + (size_t)kb * D + n0 + nbq;

    float4 a0 = {0, 0, 0, 0}, a1 = {0, 0, 0, 0}, b0, b1;
    if (valid) { a0 = *(const float4*)Ap; a1 = *(const float4*)(Ap + 4); }
    b0 = *(const float4*)Bp;
    b1 = *(const float4*)(Bp + 64);

    const int ty = tid >> 4;   // 0..15 (m dir)
    const int tx = tid & 15;   // 0..15 (n dir)
    float acc[8][8];
#pragma unroll
    for (int i = 0; i < 8; ++i)
#pragma unroll
        for (int j = 0; j < 8; ++j) acc[i][j] = 0.f;

#pragma unroll 1
    for (int kt = 0; kt < 32; ++kt) {
        {   // regs -> LDS
            float st[8];
            *(float4*)&st[0] = a0;
            *(float4*)&st[4] = a1;
#pragma unroll
            for (int i = 0; i < 8; ++i) As[ka + i][m_s] = st[i];
            *(float4*)&Bs[kb][nbq]      = b0;
            *(float4*)&Bs[kb][nbq + 64] = b1;
        }
        __syncthreads();
        if (kt < 31) {   // prefetch next k-slab into regs (hidden under compute)
            Ap += 16;
            Bp += 16 * D;
            if (valid) { a0 = *(const float4*)Ap; a1 = *(const float4*)(Ap + 4); }
            b0 = *(const float4*)Bp;
            b1 = *(const float4*)(Bp + 64);
        }
#pragma unroll
        for (int k = 0; k < 16; ++k) {
            float av[8], bv[8];
            *(float4*)&av[0] = *(const float4*)&As[k][(ty << 2)];
            *(float4*)&av[4] = *(const float4*)&As[k][64 + (ty << 2)];
            *(float4*)&bv[0] = *(const float4*)&Bs[k][(tx << 2)];
            *(float4*)&bv[4] = *(const float4*)&Bs[k][64 + (tx << 2)];
#pragma unroll
            for (int i = 0; i < 8; ++i)
#pragma unroll
                for (int j = 0; j < 8; ++j)
                    acc[i][j] = fmaf(av[i], bv[j], acc[i][j]);
        }
        __syncthreads();
    }

    // epilogue: bias (+ gate scale) then scattered row store
    const float* bbn = bb + n0;
#pragma unroll
    for (int i = 0; i < 8; ++i) {
        const int m = (i < 4) ? ((ty << 2) + i) : (64 + (ty << 2) + (i - 4));
        const int t = Ts[m];
        if (t < 0) continue;
        float s = 1.0f;
        if constexpr (GATHER) s = scale[t];
        float* Cp = C + (size_t)t * D + n0;
#pragma unroll
        for (int jh = 0; jh < 2; ++jh) {
            const int nb4 = (jh << 6) + (tx << 2);
            float4 v;
            v.x = (acc[i][jh * 4 + 0] + bbn[nb4 + 0]) * s;
            v.y = (acc[i][jh * 4 + 1] + bbn[nb4 + 1]) * s;
            v.z = (acc[i][jh * 4 + 2] + bbn[nb4 + 2]) * s;
            v.w = (acc[i][jh * 4 + 3] + bbn[nb4 + 3]) * s;
            *(float4*)(Cp + nb4) = v;
        }
    }
}

// ---------------------------------------------------------------------------
// embed[b][f] = mean_s (h + out3);  grid (8, 32), 64 s per block, atomics
// ---------------------------------------------------------------------------
__global__ __launch_bounds__(256) void k_reduce(const float* __restrict__ H,
                                                const float* __restrict__ O3,
                                                float* __restrict__ embed)
{
    const int b = blockIdx.x;
    const int sc = blockIdx.y;
    const int f = threadIdx.x;
    const size_t base = ((size_t)b * 2048 + (size_t)sc * 64) * D;
    const float* hb = H + base;
    const float* ob = O3 + base;
    float a0 = 0.f, a1 = 0.f;
#pragma unroll 4
    for (int s = 0; s < 64; ++s) {
        a0 += hb[s * D + f]       + ob[s * D + f];
        a1 += hb[s * D + f + 256] + ob[s * D + f + 256];
    }
    atomicAdd(&embed[b * D + f],       a0 * (1.0f / 2048.0f));
    atomicAdd(&embed[b * D + f + 256], a1 * (1.0f / 2048.0f));
}

// ---------------------------------------------------------------------------
// loss = mean_b ( logsumexp(embed[b]) - embed[b][y[b]] ); 8 waves, 1 block
// ---------------------------------------------------------------------------
__global__ __launch_bounds__(512) void k_loss(const float* __restrict__ embed,
                                              const int* __restrict__ y,
                                              float* __restrict__ out)
{
    __shared__ float partial[8];
    const int w = threadIdx.x >> 6;    // wave = batch row
    const int lane = threadIdx.x & 63;
    const float* row = embed + w * D;

    float v[8];
    float vmax = -1e30f;
#pragma unroll
    for (int i = 0; i < 8; ++i) {
        v[i] = row[lane + i * 64];
        vmax = fmaxf(vmax, v[i]);
    }
#pragma unroll
    for (int o = 32; o > 0; o >>= 1) vmax = fmaxf(vmax, __shfl_xor(vmax, o));
    float s = 0.f;
#pragma unroll
    for (int i = 0; i < 8; ++i) s += expf(v[i] - vmax);
#pragma unroll
    for (int o = 32; o > 0; o >>= 1) s += __shfl_xor(s, o);
    const float lse = vmax + logf(s);
    if (lane == 0) partial[w] = lse - row[y[w]];
    __syncthreads();
    if (threadIdx.x == 0) {
        float l = 0.f;
#pragma unroll
        for (int b = 0; b < 8; ++b) l += partial[b];
        out[0] = l * (1.0f / 8.0f);
    }
}

// ---------------------------------------------------------------------------
extern "C" void kernel_launch(void* const* d_in, const int* in_sizes, int n_in,
                              void* d_out, int out_size, void* d_ws, size_t ws_size,
                              hipStream_t stream)
{
    const float* x   = (const float*)d_in[0];
    const float* W1  = (const float*)d_in[1];
    const float* b1  = (const float*)d_in[2];
    const float* gw2 = (const float*)d_in[3];
    const float* We2 = (const float*)d_in[4];
    const float* be2 = (const float*)d_in[5];
    const float* gw3 = (const float*)d_in[6];
    const float* We3 = (const float*)d_in[7];
    const float* be3 = (const float*)d_in[8];
    const int*   y   = (const int*)d_in[9];
    float* out = (float*)d_out;

    // bump allocator over d_ws (total ~103 MB)
    char* ws = (char*)d_ws;
    size_t off = 0;
    auto alloc = [&](size_t bytes) -> void* {
        void* p = ws + off;
        off = (off + bytes + 255) & ~(size_t)255;
        return p;
    };
    float* w1t   = (float*)alloc((size_t)D * D * 4);
    float* h     = (float*)alloc((size_t)T_TOK * D * 4);
    float* out2  = (float*)alloc((size_t)T_TOK * D * 4);
    float* out3  = (float*)alloc((size_t)T_TOK * D * 4);
    float* p2    = (float*)alloc((size_t)T_TOK * 4);
    float* p3    = (float*)alloc((size_t)T_TOK * 4);
    int*   l2    = (int*)alloc((size_t)E * T_TOK * 4);
    int*   l3    = (int*)alloc((size_t)E * T_TOK * 4);
    int*   c2    = (int*)alloc(E * 4);
    int*   c3    = (int*)alloc(E * 4);
    int4*  de2   = (int4*)alloc(160 * 16);
    int4*  de3   = (int4*)alloc(160 * 16);
    int*   nt2   = (int*)alloc(4);
    int*   nt3   = (int*)alloc(4);
    float* embed = (float*)alloc(8 * D * 4);
    (void)ws_size; (void)in_sizes; (void)n_in; (void)out_size;

    k_zero<<<dim3(1), dim3(256), 0, stream>>>(c2, c3, embed);
    k_transpose<<<dim3(16, 16), dim3(256), 0, stream>>>(W1, w1t);

    // h = x @ W1^T + b1
    k_gemm<false><<<dim3(128, 4), dim3(256), 0, stream>>>(
        x, w1t, b1, nullptr, nullptr, nullptr, nullptr, h);

    // MoE layer 2
    k_gating<<<dim3(64), dim3(256), 0, stream>>>(h, gw2, p2, l2, c2);
    k_desc<<<dim3(1), dim3(64), 0, stream>>>(c2, de2, nt2);
    k_gemm<true><<<dim3(136, 4), dim3(256), 0, stream>>>(
        h, We2, be2, p2, l2, de2, nt2, out2);

    // MoE layer 3
    k_gating<<<dim3(64), dim3(256), 0, stream>>>(out2, gw3, p3, l3, c3);
    k_desc<<<dim3(1), dim3(64), 0, stream>>>(c3, de3, nt3);
    k_gemm<true><<<dim3(136, 4), dim3(256), 0, stream>>>(
        out2, We3, be3, p3, l3, de3, nt3, out3);

    // hidden mean + loss
    k_reduce<<<dim3(8, 32), dim3(256), 0, stream>>>(h, out3, embed);
    k_loss<<<dim3(1), dim3(512), 0, stream>>>(embed, y, out);
}

// Round 2
// 355.430 us; speedup vs baseline: 1.6921x; 1.6921x over previous
//
#include <hip/hip_runtime.h>
#include <cstdint>

#define T_TOK 16384   // B*S = 8*2048
#define D     512
#define E     8

typedef __attribute__((ext_vector_type(4))) float f32x4;
typedef __attribute__((ext_vector_type(8))) short short8v;
typedef __attribute__((ext_vector_type(8))) unsigned short u16x8;

__device__ __forceinline__ unsigned short f2bf(float f) {
    unsigned u = __float_as_uint(f);
    u += 0x7FFF + ((u >> 16) & 1);          // RNE
    return (unsigned short)(u >> 16);
}
__device__ __forceinline__ float bf2f(unsigned short h) {
    return __uint_as_float((unsigned)h << 16);
}
// 16B-granule XOR swizzle inside a 64B LDS row: fragment reads 2-way (free)
__device__ __forceinline__ int swz(int r, int g) {
    return (r << 6) + (((g ^ ((r >> 1) & 3)) & 3) << 4);
}

// ---------------------------------------------------------------------------
// W1 -> bf16 hi/lo (already [n][k] layout for h = x @ W1^T)
// ---------------------------------------------------------------------------
__global__ __launch_bounds__(256) void k_conv_w1(const float* __restrict__ W,
                                                 unsigned short* __restrict__ hi,
                                                 unsigned short* __restrict__ lo)
{
    const int i = (blockIdx.x * 256 + threadIdx.x) * 4;
    const float4 v = *(const float4*)(W + i);
    const float f[4] = {v.x, v.y, v.z, v.w};
    unsigned short h[4], l[4];
#pragma unroll
    for (int j = 0; j < 4; ++j) {
        h[j] = f2bf(f[j]);
        l[j] = f2bf(f[j] - bf2f(h[j]));
    }
    *(uint2*)(hi + i) = *(uint2*)h;
    *(uint2*)(lo + i) = *(uint2*)l;
}

// ---------------------------------------------------------------------------
// We[e][k][n] -> transposed bf16 hi/lo  WT[e][n][k]   (both MoE layers)
// ---------------------------------------------------------------------------
__global__ __launch_bounds__(256) void k_prep_we(const float* __restrict__ We2,
                                                 const float* __restrict__ We3,
                                                 unsigned short* __restrict__ hi2,
                                                 unsigned short* __restrict__ lo2,
                                                 unsigned short* __restrict__ hi3,
                                                 unsigned short* __restrict__ lo3)
{
    __shared__ float t[32][33];
    const int z = blockIdx.z;            // 0..15 : expert + 8*layer
    const int e = z & 7;
    const float* src = (z < 8 ? We2 : We3) + ((size_t)e << 18);
    unsigned short* dh = (z < 8 ? hi2 : hi3) + ((size_t)e << 18);
    unsigned short* dl = (z < 8 ? lo2 : lo3) + ((size_t)e << 18);
    const int k0 = blockIdx.x << 5, n0 = blockIdx.y << 5;
    const int tx = threadIdx.x & 31, ty = threadIdx.x >> 5;
#pragma unroll
    for (int i = 0; i < 32; i += 8)
        t[ty + i][tx] = src[(size_t)(k0 + ty + i) * D + n0 + tx];
    __syncthreads();
#pragma unroll
    for (int i = 0; i < 32; i += 8) {
        const float f = t[tx][ty + i];
        const unsigned short h = f2bf(f);
        const unsigned short l = f2bf(f - bf2f(h));
        const size_t o = (size_t)(n0 + ty + i) * D + k0 + tx;
        dh[o] = h; dl[o] = l;
    }
}

// ---------------------------------------------------------------------------
__global__ void k_zero(int* c2, int* c3, float* embed)
{
    const int tid = threadIdx.x;
    if (tid < E) { c2[tid] = 0; c3[tid] = 0; }
    for (int i = tid; i < 8 * D; i += 256) embed[i] = 0.f;
}

// ---------------------------------------------------------------------------
// Gating: fp32 logits -> top-1 expert + gate prob; bucket tokens by expert
// ---------------------------------------------------------------------------
__global__ __launch_bounds__(256) void k_gating(const float* __restrict__ H,
                                                const float* __restrict__ gw,
                                                float* __restrict__ p,
                                                int* __restrict__ lists,
                                                int* __restrict__ counts)
{
    __shared__ float gws[D * E];
    const int tid = threadIdx.x;
    for (int i = tid; i < D * E; i += 256) gws[i] = gw[i];
    __syncthreads();

    const int t = blockIdx.x * 256 + tid;
    const float* hrow = H + (size_t)t * D;
    float acc[E];
#pragma unroll
    for (int e = 0; e < E; ++e) acc[e] = 0.f;

    for (int d = 0; d < D; d += 4) {
        const float4 hv = *(const float4*)(hrow + d);
#pragma unroll
        for (int e = 0; e < E; ++e)
            acc[e] += hv.x * gws[(d + 0) * E + e] + hv.y * gws[(d + 1) * E + e]
                    + hv.z * gws[(d + 2) * E + e] + hv.w * gws[(d + 3) * E + e];
    }

    float m = acc[0]; int mi = 0;
#pragma unroll
    for (int e = 1; e < E; ++e)
        if (acc[e] > m) { m = acc[e]; mi = e; }   // strict > == argmax first-max
    float ssum = 0.f;
#pragma unroll
    for (int e = 0; e < E; ++e) ssum += expf(acc[e] - m);
    p[t] = 1.0f / ssum;

    const int lane = tid & 63;
    const unsigned long long below = (lane == 0) ? 0ULL : ((~0ULL) >> (64 - lane));
#pragma unroll 1
    for (int e = 0; e < E; ++e) {
        const unsigned long long mask = __ballot(mi == e);
        if (mi == e) {
            const int leader = __ffsll((unsigned long long)mask) - 1;
            int base = 0;
            if (lane == leader) base = atomicAdd(&counts[e], (int)__popcll(mask));
            base = __shfl(base, leader);
            const int offs = (int)__popcll(mask & below);
            lists[e * T_TOK + base + offs] = t;
        }
    }
}

// ---------------------------------------------------------------------------
__global__ void k_desc(const int* __restrict__ counts, int4* __restrict__ desc,
                       int* __restrict__ ntiles)
{
    if (threadIdx.x == 0) {
        int total = 0;
        for (int e = 0; e < E; ++e) {
            const int c = counts[e];
            for (int m = 0; m < c; m += 128) {
                desc[total++] = make_int4(e, e * T_TOK + m, min(128, c - m), 0);
            }
        }
        *ntiles = total;
    }
}

// ---------------------------------------------------------------------------
// Split-bf16 MFMA GEMM: 128x128 tile, BK=32, 4 waves (2x2), 16x16x32 bf16.
// A fp32 in global, converted to hi/lo bf16 during LDS staging.
// B pre-converted transposed bf16 hi/lo [n][k].
// acc += Ahi*Bhi + Ahi*Blo + Alo*Bhi  (fp32-equivalent precision)
// ---------------------------------------------------------------------------
template <bool GATHER>
__global__ __launch_bounds__(256, 2) void k_gemm_mfma(
    const float* __restrict__ A,
    const unsigned short* __restrict__ Bh,
    const unsigned short* __restrict__ Bl,
    const float* __restrict__ bias,
    const float* __restrict__ scale,
    const int* __restrict__ lists,
    const int4* __restrict__ desc,
    const int* __restrict__ ntiles,
    float* __restrict__ C)
{
    __shared__ __align__(16) char sAh[8192];
    __shared__ __align__(16) char sAl[8192];
    __shared__ __align__(16) char sBh[8192];
    __shared__ __align__(16) char sBl[8192];
    __shared__ int Ts[128];

    const int tid = threadIdx.x;
    const int mt = blockIdx.x;
    int listoff = 0, mcnt = 128;
    size_t boff = 0;
    const float* bb = bias;
    if constexpr (GATHER) {
        if (mt >= *ntiles) return;
        const int4 dsc = desc[mt];
        boff = (size_t)dsc.x << 18;
        bb = bias + (dsc.x << 9);
        listoff = dsc.y;
        mcnt = dsc.z;
    }
    const int n0 = blockIdx.y << 7;

    if (tid < 128) {
        int t;
        if constexpr (GATHER) t = (tid < mcnt) ? lists[listoff + tid] : -1;
        else                  t = (mt << 7) + tid;
        Ts[tid] = t;
    }
    __syncthreads();

    // ---- staging assignment: thread -> (row, k-half) ----
    const int srow = tid >> 1;
    const int sk   = (tid & 1) << 4;      // 0 or 16 (elements)
    const int tA   = Ts[srow];
    const float* ap = A + (size_t)(tA < 0 ? 0 : tA) * D + sk;
    const unsigned short* bph = Bh + boff + (size_t)(n0 + srow) * D + sk;
    const unsigned short* bpl = Bl + boff + (size_t)(n0 + srow) * D + sk;
    const int g0  = sk >> 3;              // granule 0 or 2
    const int wa0 = swz(srow, g0), wa1 = swz(srow, g0 + 1);

    float4 av0 = *(const float4*)ap,        av1 = *(const float4*)(ap + 4),
           av2 = *(const float4*)(ap + 8),  av3 = *(const float4*)(ap + 12);
    uint4 bh0 = *(const uint4*)bph, bh1 = *(const uint4*)(bph + 8);
    uint4 bl0 = *(const uint4*)bpl, bl1 = *(const uint4*)(bpl + 8);

    // ---- wave / fragment ids ----
    const int wid = tid >> 6, lane = tid & 63;
    const int wr = (wid >> 1) << 6;       // wave m-offset (0/64)
    const int wc = (wid & 1) << 6;        // wave n-offset (0/64)
    const int fr = lane & 15;
    const int fg = lane >> 4;             // k-granule 0..3

    f32x4 acc[4][4] = {};

#pragma unroll 1
    for (int kt = 0; kt < 16; ++kt) {
        // convert current A regs -> hi/lo bf16
        u16x8 h0, h1, l0, l1;
        {
            float f[16];
            *(float4*)&f[0] = av0; *(float4*)&f[4]  = av1;
            *(float4*)&f[8] = av2; *(float4*)&f[12] = av3;
#pragma unroll
            for (int i = 0; i < 8; ++i) {
                const unsigned short hh = f2bf(f[i]);
                h0[i] = hh;
                l0[i] = f2bf(f[i] - bf2f(hh));
            }
#pragma unroll
            for (int i = 0; i < 8; ++i) {
                const unsigned short hh = f2bf(f[8 + i]);
                h1[i] = hh;
                l1[i] = f2bf(f[8 + i] - bf2f(hh));
            }
        }
        __syncthreads();                    // previous MFMA reads done
        *(u16x8*)(sAh + wa0) = h0;  *(u16x8*)(sAh + wa1) = h1;
        *(u16x8*)(sAl + wa0) = l0;  *(u16x8*)(sAl + wa1) = l1;
        *(uint4*)(sBh + wa0) = bh0; *(uint4*)(sBh + wa1) = bh1;
        *(uint4*)(sBl + wa0) = bl0; *(uint4*)(sBl + wa1) = bl1;
        __syncthreads();
        if (kt < 15) {                      // prefetch next k-slab into regs
            ap += 32; bph += 32; bpl += 32;
            av0 = *(const float4*)ap;       av1 = *(const float4*)(ap + 4);
            av2 = *(const float4*)(ap + 8); av3 = *(const float4*)(ap + 12);
            bh0 = *(const uint4*)bph; bh1 = *(const uint4*)(bph + 8);
            bl0 = *(const uint4*)bpl; bl1 = *(const uint4*)(bpl + 8);
        }

        short8v a_h[4], a_l[4], b_h[4], b_l[4];
#pragma unroll
        for (int i = 0; i < 4; ++i) {
            const int r = wr + i * 16 + fr;
            a_h[i] = *(const short8v*)(sAh + swz(r, fg));
            a_l[i] = *(const short8v*)(sAl + swz(r, fg));
        }
#pragma unroll
        for (int j = 0; j < 4; ++j) {
            const int r = wc + j * 16 + fr;
            b_h[j] = *(const short8v*)(sBh + swz(r, fg));
            b_l[j] = *(const short8v*)(sBl + swz(r, fg));
        }
#pragma unroll
        for (int i = 0; i < 4; ++i)
#pragma unroll
            for (int j = 0; j < 4; ++j) {
                acc[i][j] = __builtin_amdgcn_mfma_f32_16x16x32_bf16(a_h[i], b_h[j], acc[i][j], 0, 0, 0);
                acc[i][j] = __builtin_amdgcn_mfma_f32_16x16x32_bf16(a_h[i], b_l[j], acc[i][j], 0, 0, 0);
                acc[i][j] = __builtin_amdgcn_mfma_f32_16x16x32_bf16(a_l[i], b_h[j], acc[i][j], 0, 0, 0);
            }
    }

    // ---- epilogue: bias (+ gate scale), scattered row store ----
    float bj[4];
#pragma unroll
    for (int j = 0; j < 4; ++j) bj[j] = bb[n0 + wc + j * 16 + fr];
#pragma unroll
    for (int i = 0; i < 4; ++i) {
#pragma unroll
        for (int r = 0; r < 4; ++r) {
            const int m = wr + i * 16 + fg * 4 + r;   // C row = (lane>>4)*4 + reg
            const int t = Ts[m];
            if (t < 0) continue;
            float s = 1.f;
            if constexpr (GATHER) s = scale[t];
            float* cp = C + (size_t)t * D + n0 + wc;
#pragma unroll
            for (int j = 0; j < 4; ++j)
                cp[j * 16 + fr] = (acc[i][j][r] + bj[j]) * s;
        }
    }
}

// ---------------------------------------------------------------------------
__global__ __launch_bounds__(256) void k_reduce(const float* __restrict__ H,
                                                const float* __restrict__ O3,
                                                float* __restrict__ embed)
{
    const int b = blockIdx.x;
    const int sc = blockIdx.y;
    const int f = threadIdx.x;
    const size_t base = ((size_t)b * 2048 + (size_t)sc * 64) * D;
    const float* hb = H + base;
    const float* ob = O3 + base;
    float a0 = 0.f, a1 = 0.f;
#pragma unroll 4
    for (int s = 0; s < 64; ++s) {
        a0 += hb[s * D + f]       + ob[s * D + f];
        a1 += hb[s * D + f + 256] + ob[s * D + f + 256];
    }
    atomicAdd(&embed[b * D + f],       a0 * (1.0f / 2048.0f));
    atomicAdd(&embed[b * D + f + 256], a1 * (1.0f / 2048.0f));
}

// ---------------------------------------------------------------------------
__global__ __launch_bounds__(512) void k_loss(const float* __restrict__ embed,
                                              const int* __restrict__ y,
                                              float* __restrict__ out)
{
    __shared__ float partial[8];
    const int w = threadIdx.x >> 6;
    const int lane = threadIdx.x & 63;
    const float* row = embed + w * D;

    float v[8];
    float vmax = -1e30f;
#pragma unroll
    for (int i = 0; i < 8; ++i) {
        v[i] = row[lane + i * 64];
        vmax = fmaxf(vmax, v[i]);
    }
#pragma unroll
    for (int o = 32; o > 0; o >>= 1) vmax = fmaxf(vmax, __shfl_xor(vmax, o));
    float s = 0.f;
#pragma unroll
    for (int i = 0; i < 8; ++i) s += expf(v[i] - vmax);
#pragma unroll
    for (int o = 32; o > 0; o >>= 1) s += __shfl_xor(s, o);
    const float lse = vmax + logf(s);
    if (lane == 0) partial[w] = lse - row[y[w]];
    __syncthreads();
    if (threadIdx.x == 0) {
        float l = 0.f;
#pragma unroll
        for (int b = 0; b < 8; ++b) l += partial[b];
        out[0] = l * (1.0f / 8.0f);
    }
}

// ---------------------------------------------------------------------------
extern "C" void kernel_launch(void* const* d_in, const int* in_sizes, int n_in,
                              void* d_out, int out_size, void* d_ws, size_t ws_size,
                              hipStream_t stream)
{
    const float* x   = (const float*)d_in[0];
    const float* W1  = (const float*)d_in[1];
    const float* b1  = (const float*)d_in[2];
    const float* gw2 = (const float*)d_in[3];
    const float* We2 = (const float*)d_in[4];
    const float* be2 = (const float*)d_in[5];
    const float* gw3 = (const float*)d_in[6];
    const float* We3 = (const float*)d_in[7];
    const float* be3 = (const float*)d_in[8];
    const int*   y   = (const int*)d_in[9];
    float* out = (float*)d_out;

    char* ws = (char*)d_ws;
    size_t off = 0;
    auto alloc = [&](size_t bytes) -> void* {
        void* p = ws + off;
        off = (off + bytes + 255) & ~(size_t)255;
        return p;
    };
    float* h     = (float*)alloc((size_t)T_TOK * D * 4);
    float* out2  = (float*)alloc((size_t)T_TOK * D * 4);
    float* out3  = (float*)alloc((size_t)T_TOK * D * 4);
    unsigned short* b1h  = (unsigned short*)alloc((size_t)D * D * 2);
    unsigned short* b1l  = (unsigned short*)alloc((size_t)D * D * 2);
    unsigned short* we2h = (unsigned short*)alloc((size_t)E * D * D * 2);
    unsigned short* we2l = (unsigned short*)alloc((size_t)E * D * D * 2);
    unsigned short* we3h = (unsigned short*)alloc((size_t)E * D * D * 2);
    unsigned short* we3l = (unsigned short*)alloc((size_t)E * D * D * 2);
    float* p2    = (float*)alloc((size_t)T_TOK * 4);
    float* p3    = (float*)alloc((size_t)T_TOK * 4);
    int*   l2    = (int*)alloc((size_t)E * T_TOK * 4);
    int*   l3    = (int*)alloc((size_t)E * T_TOK * 4);
    int*   c2    = (int*)alloc(E * 4);
    int*   c3    = (int*)alloc(E * 4);
    int4*  de2   = (int4*)alloc(160 * 16);
    int4*  de3   = (int4*)alloc(160 * 16);
    int*   nt2   = (int*)alloc(4);
    int*   nt3   = (int*)alloc(4);
    float* embed = (float*)alloc(8 * D * 4);
    (void)ws_size; (void)in_sizes; (void)n_in; (void)out_size;

    k_zero<<<dim3(1), dim3(256), 0, stream>>>(c2, c3, embed);
    k_conv_w1<<<dim3(256), dim3(256), 0, stream>>>(W1, b1h, b1l);
    k_prep_we<<<dim3(16, 16, 16), dim3(256), 0, stream>>>(We2, We3, we2h, we2l, we3h, we3l);

    // h = x @ W1^T + b1
    k_gemm_mfma<false><<<dim3(128, 4), dim3(256), 0, stream>>>(
        x, b1h, b1l, b1, nullptr, nullptr, nullptr, nullptr, h);

    // MoE layer 2
    k_gating<<<dim3(64), dim3(256), 0, stream>>>(h, gw2, p2, l2, c2);
    k_desc<<<dim3(1), dim3(64), 0, stream>>>(c2, de2, nt2);
    k_gemm_mfma<true><<<dim3(136, 4), dim3(256), 0, stream>>>(
        h, we2h, we2l, be2, p2, l2, de2, nt2, out2);

    // MoE layer 3
    k_gating<<<dim3(64), dim3(256), 0, stream>>>(out2, gw3, p3, l3, c3);
    k_desc<<<dim3(1), dim3(64), 0, stream>>>(c3, de3, nt3);
    k_gemm_mfma<true><<<dim3(136, 4), dim3(256), 0, stream>>>(
        out2, we3h, we3l, be3, p3, l3, de3, nt3, out3);

    // hidden mean + loss
    k_reduce<<<dim3(8, 32), dim3(256), 0, stream>>>(h, out3, embed);
    k_loss<<<dim3(1), dim3(512), 0, stream>>>(embed, y, out);
}

// Round 7
// 267.763 us; speedup vs baseline: 2.2461x; 1.3274x over previous
//
#include <hip/hip_runtime.h>
#include <cstdint>

#define T_TOK 16384   // B*S = 8*2048
#define D     512
#define E     8

typedef __attribute__((ext_vector_type(4))) float f32x4;
typedef __attribute__((ext_vector_type(8))) short short8v;
typedef __attribute__((ext_vector_type(8))) unsigned short u16x8;

__device__ __forceinline__ unsigned short f2bf(float f) {
    unsigned u = __float_as_uint(f);
    u += 0x7FFF + ((u >> 16) & 1);          // RNE
    return (unsigned short)(u >> 16);
}
__device__ __forceinline__ float bf2f(unsigned short h) {
    return __uint_as_float((unsigned)h << 16);
}
// 16B-granule XOR swizzle inside a 64B LDS row: fragment reads 2-way (free)
__device__ __forceinline__ int swz(int r, int g) {
    return (r << 6) + (((g ^ ((r >> 1) & 3)) & 3) << 4);
}

// ---------------------------------------------------------------------------
// W1 -> bf16 hi/lo  (+ block 256 zeroes counts/embed; ws is 0xAA-poisoned)
// ---------------------------------------------------------------------------
__global__ __launch_bounds__(256) void k_conv_w1(const float* __restrict__ W,
                                                 unsigned short* __restrict__ hi,
                                                 unsigned short* __restrict__ lo,
                                                 int* __restrict__ c2,
                                                 int* __restrict__ c3,
                                                 float* __restrict__ embed)
{
    const int tid = threadIdx.x;
    if (blockIdx.x == 256) {
        if (tid < E) { c2[tid] = 0; c3[tid] = 0; }
        for (int i = tid; i < 8 * D; i += 256) embed[i] = 0.f;
        return;
    }
    const int i = (blockIdx.x * 256 + tid) * 4;
    const float4 v = *(const float4*)(W + i);
    const float f[4] = {v.x, v.y, v.z, v.w};
    unsigned short h[4], l[4];
#pragma unroll
    for (int j = 0; j < 4; ++j) {
        h[j] = f2bf(f[j]);
        l[j] = f2bf(f[j] - bf2f(h[j]));
    }
    *(uint2*)(hi + i) = *(uint2*)h;
    *(uint2*)(lo + i) = *(uint2*)l;
}

// ---------------------------------------------------------------------------
// We[e][k][n] -> transposed bf16 hi/lo  WT[e][n][k]; uint2 stores
// ---------------------------------------------------------------------------
__global__ __launch_bounds__(256) void k_prep_we(const float* __restrict__ We2,
                                                 const float* __restrict__ We3,
                                                 unsigned short* __restrict__ hi2,
                                                 unsigned short* __restrict__ lo2,
                                                 unsigned short* __restrict__ hi3,
                                                 unsigned short* __restrict__ lo3)
{
    __shared__ float t[32][33];
    const int z = blockIdx.z;            // 0..15 : expert + 8*layer
    const int e = z & 7;
    const float* src = (z < 8 ? We2 : We3) + ((size_t)e << 18);
    unsigned short* dh = (z < 8 ? hi2 : hi3) + ((size_t)e << 18);
    unsigned short* dl = (z < 8 ? lo2 : lo3) + ((size_t)e << 18);
    const int k0 = blockIdx.x << 5, n0 = blockIdx.y << 5;
    const int tx = threadIdx.x & 31, ty = threadIdx.x >> 5;
#pragma unroll
    for (int i = 0; i < 32; i += 8)
        t[ty + i][tx] = src[(size_t)(k0 + ty + i) * D + n0 + tx];
    __syncthreads();
    const int n  = threadIdx.x >> 3;         // 0..31 out row (n)
    const int kc = (threadIdx.x & 7) << 2;   // 0..28 k chunk
    unsigned short h4[4], l4[4];
#pragma unroll
    for (int j = 0; j < 4; ++j) {
        const float f = t[kc + j][n];
        h4[j] = f2bf(f);
        l4[j] = f2bf(f - bf2f(h4[j]));
    }
    const size_t o = (size_t)(n0 + n) * D + k0 + kc;
    *(uint2*)(dh + o) = *(uint2*)h4;
    *(uint2*)(dl + o) = *(uint2*)l4;
}

// ---------------------------------------------------------------------------
// Gating (cooperative): 8 threads/token x 64 dims, 2 tokens per slot.
// grid 256 blocks x 256 threads = 64 tokens/block.
// ---------------------------------------------------------------------------
__global__ __launch_bounds__(256) void k_gating(const float* __restrict__ H,
                                                const float* __restrict__ gw,
                                                float* __restrict__ p,
                                                int* __restrict__ lists,
                                                int* __restrict__ counts)
{
    __shared__ float gws[D * E];          // 16 KB, [d][e]
    __shared__ int histo[E], basex[E];
    const int tid = threadIdx.x;
    for (int i = tid; i < D * E; i += 256) gws[i] = gw[i];
    if (tid < E) histo[tid] = 0;
    __syncthreads();

    const int part = tid & 7;             // 64-dim slice
    const int slot = tid >> 3;            // 0..31
    const int t0 = (blockIdx.x << 6) + slot;
    const int t1 = t0 + 32;
    const int d0 = part << 6;

    float a0[E], a1[E];
#pragma unroll
    for (int e = 0; e < E; ++e) { a0[e] = 0.f; a1[e] = 0.f; }
    const float* h0 = H + (size_t)t0 * D + d0;
    const float* h1 = H + (size_t)t1 * D + d0;
#pragma unroll 4
    for (int i = 0; i < 64; i += 4) {
        const float4 v0 = *(const float4*)(h0 + i);
        const float4 v1 = *(const float4*)(h1 + i);
        const float* gp = gws + (size_t)(d0 + i) * E;
#pragma unroll
        for (int j = 0; j < 4; ++j) {
            const f32x4 gA = *(const f32x4*)(gp + j * E);
            const f32x4 gB = *(const f32x4*)(gp + j * E + 4);
            const float x0 = (j == 0) ? v0.x : (j == 1) ? v0.y : (j == 2) ? v0.z : v0.w;
            const float x1 = (j == 0) ? v1.x : (j == 1) ? v1.y : (j == 2) ? v1.z : v1.w;
#pragma unroll
            for (int e = 0; e < 4; ++e) {
                a0[e]     += x0 * gA[e];
                a0[e + 4] += x0 * gB[e];
                a1[e]     += x1 * gA[e];
                a1[e + 4] += x1 * gB[e];
            }
        }
    }
#pragma unroll
    for (int e = 0; e < E; ++e) {
#pragma unroll
        for (int o = 1; o < 8; o <<= 1) {
            a0[e] += __shfl_xor(a0[e], o, 8);
            a1[e] += __shfl_xor(a1[e], o, 8);
        }
    }

    int mi0 = 0, mi1 = 0, r0 = 0, r1 = 0;
    if (part == 0) {
        float m0 = a0[0], m1 = a1[0];
#pragma unroll
        for (int e = 1; e < E; ++e) {      // strict > == argmax first-max
            if (a0[e] > m0) { m0 = a0[e]; mi0 = e; }
            if (a1[e] > m1) { m1 = a1[e]; mi1 = e; }
        }
        float s0 = 0.f, s1 = 0.f;
#pragma unroll
        for (int e = 0; e < E; ++e) { s0 += expf(a0[e] - m0); s1 += expf(a1[e] - m1); }
        p[t0] = 1.0f / s0;
        p[t1] = 1.0f / s1;
        r0 = atomicAdd(&histo[mi0], 1);
        r1 = atomicAdd(&histo[mi1], 1);
    }
    __syncthreads();
    if (tid < E) basex[tid] = atomicAdd(&counts[tid], histo[tid]);
    __syncthreads();
    if (part == 0) {
        lists[mi0 * T_TOK + basex[mi0] + r0] = t0;
        lists[mi1 * T_TOK + basex[mi1] + r1] = t1;
    }
}

// ---------------------------------------------------------------------------
// Split-bf16 MFMA GEMM: 128x128 tile, BK=32, 4 waves (2x2), 16x16x32 bf16.
// acc += Ahi*Bhi + Ahi*Blo + Alo*Bhi  (fp32-equivalent precision)
// 1-D grid, XCD-bijective swizzle + y-fastest (A-slab L2 locality).
// GATHER blocks derive their (expert, m-start) from counts[] directly.
// ---------------------------------------------------------------------------
template <bool GATHER>
__global__ __launch_bounds__(256, 2) void k_gemm_mfma(
    const float* __restrict__ A,
    const unsigned short* __restrict__ Bh,
    const unsigned short* __restrict__ Bl,
    const float* __restrict__ bias,
    const float* __restrict__ scale,
    const int* __restrict__ lists,
    const int* __restrict__ counts,
    float* __restrict__ C)
{
    __shared__ __align__(16) char sAh[8192];
    __shared__ __align__(16) char sAl[8192];
    __shared__ __align__(16) char sBh[8192];
    __shared__ __align__(16) char sBl[8192];
    __shared__ int Ts[128];

    const int tid = threadIdx.x;
    // block mapping: XCD-bijective swizzle, then y(n-tile)-fastest
    const int cpx = gridDim.x >> 3;               // 512->64, 544->68
    const int wg  = (blockIdx.x & 7) * cpx + (blockIdx.x >> 3);
    const int mt  = wg >> 2;
    const int n0  = (wg & 3) << 7;

    int listoff = 0, mcnt = 128;
    size_t boff = 0;
    const float* bb = bias;
    if constexpr (GATHER) {
        int acc8 = 0, eSel = -1, mstart = 0;
#pragma unroll
        for (int i = 0; i < 8; ++i) {
            const int c = counts[i];
            const int nt = (c + 127) >> 7;
            if (eSel < 0 && mt < acc8 + nt) { eSel = i; mstart = (mt - acc8) << 7; }
            acc8 += nt;
        }
        if (eSel < 0) return;
        mcnt = min(128, counts[eSel] - mstart);
        listoff = eSel * T_TOK + mstart;
        boff = (size_t)eSel << 18;
        bb = bias + (eSel << 9);
    }

    if (tid < 128) {
        int t;
        if constexpr (GATHER) t = (tid < mcnt) ? lists[listoff + tid] : -1;
        else                  t = (mt << 7) + tid;
        Ts[tid] = t;
    }
    __syncthreads();

    // ---- staging assignment: thread -> (row, k-half) ----
    const int srow = tid >> 1;
    const int sk   = (tid & 1) << 4;      // 0 or 16 (elements)
    const int tA   = Ts[srow];
    const float* ap = A + (size_t)(tA < 0 ? 0 : tA) * D + sk;
    const unsigned short* bph = Bh + boff + (size_t)(n0 + srow) * D + sk;
    const unsigned short* bpl = Bl + boff + (size_t)(n0 + srow) * D + sk;
    const int g0  = sk >> 3;              // granule 0 or 2
    const int wa0 = swz(srow, g0), wa1 = swz(srow, g0 + 1);

    float4 av0 = *(const float4*)ap,        av1 = *(const float4*)(ap + 4),
           av2 = *(const float4*)(ap + 8),  av3 = *(const float4*)(ap + 12);
    uint4 bh0 = *(const uint4*)bph, bh1 = *(const uint4*)(bph + 8);
    uint4 bl0 = *(const uint4*)bpl, bl1 = *(const uint4*)(bpl + 8);

    // ---- wave / fragment ids ----
    const int wid = tid >> 6, lane = tid & 63;
    const int wr = (wid >> 1) << 6;       // wave m-offset (0/64)
    const int wc = (wid & 1) << 6;        // wave n-offset (0/64)
    const int fr = lane & 15;
    const int fg = lane >> 4;             // k-granule 0..3

    f32x4 acc[4][4] = {};

#pragma unroll 1
    for (int kt = 0; kt < 16; ++kt) {
        // convert current A regs -> hi/lo bf16
        u16x8 h0, h1, l0, l1;
        {
            float f[16];
            *(float4*)&f[0] = av0; *(float4*)&f[4]  = av1;
            *(float4*)&f[8] = av2; *(float4*)&f[12] = av3;
#pragma unroll
            for (int i = 0; i < 8; ++i) {
                const unsigned short hh = f2bf(f[i]);
                h0[i] = hh;
                l0[i] = f2bf(f[i] - bf2f(hh));
            }
#pragma unroll
            for (int i = 0; i < 8; ++i) {
                const unsigned short hh = f2bf(f[8 + i]);
                h1[i] = hh;
                l1[i] = f2bf(f[8 + i] - bf2f(hh));
            }
        }
        __syncthreads();                    // previous MFMA reads done
        *(u16x8*)(sAh + wa0) = h0;  *(u16x8*)(sAh + wa1) = h1;
        *(u16x8*)(sAl + wa0) = l0;  *(u16x8*)(sAl + wa1) = l1;
        *(uint4*)(sBh + wa0) = bh0; *(uint4*)(sBh + wa1) = bh1;
        *(uint4*)(sBl + wa0) = bl0; *(uint4*)(sBl + wa1) = bl1;
        __syncthreads();
        if (kt < 15) {                      // prefetch next k-slab into regs
            ap += 32; bph += 32; bpl += 32;
            av0 = *(const float4*)ap;       av1 = *(const float4*)(ap + 4);
            av2 = *(const float4*)(ap + 8); av3 = *(const float4*)(ap + 12);
            bh0 = *(const uint4*)bph; bh1 = *(const uint4*)(bph + 8);
            bl0 = *(const uint4*)bpl; bl1 = *(const uint4*)(bpl + 8);
        }

        short8v a_h[4], a_l[4], b_h[4], b_l[4];
#pragma unroll
        for (int i = 0; i < 4; ++i) {
            const int r = wr + i * 16 + fr;
            a_h[i] = *(const short8v*)(sAh + swz(r, fg));
            a_l[i] = *(const short8v*)(sAl + swz(r, fg));
        }
#pragma unroll
        for (int j = 0; j < 4; ++j) {
            const int r = wc + j * 16 + fr;
            b_h[j] = *(const short8v*)(sBh + swz(r, fg));
            b_l[j] = *(const short8v*)(sBl + swz(r, fg));
        }
#pragma unroll
        for (int i = 0; i < 4; ++i)
#pragma unroll
            for (int j = 0; j < 4; ++j) {
                acc[i][j] = __builtin_amdgcn_mfma_f32_16x16x32_bf16(a_h[i], b_h[j], acc[i][j], 0, 0, 0);
                acc[i][j] = __builtin_amdgcn_mfma_f32_16x16x32_bf16(a_h[i], b_l[j], acc[i][j], 0, 0, 0);
                acc[i][j] = __builtin_amdgcn_mfma_f32_16x16x32_bf16(a_l[i], b_h[j], acc[i][j], 0, 0, 0);
            }
    }

    // ---- epilogue: bias (+ gate scale), scattered row store ----
    float bj[4];
#pragma unroll
    for (int j = 0; j < 4; ++j) bj[j] = bb[n0 + wc + j * 16 + fr];
#pragma unroll
    for (int i = 0; i < 4; ++i) {
#pragma unroll
        for (int r = 0; r < 4; ++r) {
            const int m = wr + i * 16 + fg * 4 + r;   // C row = (lane>>4)*4 + reg
            const int t = Ts[m];
            if (t < 0) continue;
            float s = 1.f;
            if constexpr (GATHER) s = scale[t];
            float* cp = C + (size_t)t * D + n0 + wc;
#pragma unroll
            for (int j = 0; j < 4; ++j)
                cp[j * 16 + fr] = (acc[i][j][r] + bj[j]) * s;
        }
    }
}

// ---------------------------------------------------------------------------
// embed[b][f] += mean_s (h + out3);  grid (8, 64), 32 s per block
// ---------------------------------------------------------------------------
__global__ __launch_bounds__(256) void k_reduce(const float* __restrict__ H,
                                                const float* __restrict__ O3,
                                                float* __restrict__ embed)
{
    const int b = blockIdx.x;
    const int sc = blockIdx.y;
    const int f = threadIdx.x;
    const size_t base = ((size_t)b * 2048 + (size_t)sc * 32) * D;
    const float* hb = H + base;
    const float* ob = O3 + base;
    float a0 = 0.f, a1 = 0.f;
#pragma unroll 4
    for (int s = 0; s < 32; ++s) {
        a0 += hb[s * D + f]       + ob[s * D + f];
        a1 += hb[s * D + f + 256] + ob[s * D + f + 256];
    }
    atomicAdd(&embed[b * D + f],       a0 * (1.0f / 2048.0f));
    atomicAdd(&embed[b * D + f + 256], a1 * (1.0f / 2048.0f));
}

// ---------------------------------------------------------------------------
__global__ __launch_bounds__(512) void k_loss(const float* __restrict__ embed,
                                              const int* __restrict__ y,
                                              float* __restrict__ out)
{
    __shared__ float partial[8];
    const int w = threadIdx.x >> 6;
    const int lane = threadIdx.x & 63;
    const float* row = embed + w * D;

    float v[8];
    float vmax = -1e30f;
#pragma unroll
    for (int i = 0; i < 8; ++i) {
        v[i] = row[lane + i * 64];
        vmax = fmaxf(vmax, v[i]);
    }
#pragma unroll
    for (int o = 32; o > 0; o >>= 1) vmax = fmaxf(vmax, __shfl_xor(vmax, o));
    float s = 0.f;
#pragma unroll
    for (int i = 0; i < 8; ++i) s += expf(v[i] - vmax);
#pragma unroll
    for (int o = 32; o > 0; o >>= 1) s += __shfl_xor(s, o);
    const float lse = vmax + logf(s);
    if (lane == 0) partial[w] = lse - row[y[w]];
    __syncthreads();
    if (threadIdx.x == 0) {
        float l = 0.f;
#pragma unroll
        for (int b = 0; b < 8; ++b) l += partial[b];
        out[0] = l * (1.0f / 8.0f);
    }
}

// ---------------------------------------------------------------------------
extern "C" void kernel_launch(void* const* d_in, const int* in_sizes, int n_in,
                              void* d_out, int out_size, void* d_ws, size_t ws_size,
                              hipStream_t stream)
{
    const float* x   = (const float*)d_in[0];
    const float* W1  = (const float*)d_in[1];
    const float* b1  = (const float*)d_in[2];
    const float* gw2 = (const float*)d_in[3];
    const float* We2 = (const float*)d_in[4];
    const float* be2 = (const float*)d_in[5];
    const float* gw3 = (const float*)d_in[6];
    const float* We3 = (const float*)d_in[7];
    const float* be3 = (const float*)d_in[8];
    const int*   y   = (const int*)d_in[9];
    float* out = (float*)d_out;

    char* ws = (char*)d_ws;
    size_t off = 0;
    auto alloc = [&](size_t bytes) -> void* {
        void* p = ws + off;
        off = (off + bytes + 255) & ~(size_t)255;
        return p;
    };
    float* h     = (float*)alloc((size_t)T_TOK * D * 4);
    float* out2  = (float*)alloc((size_t)T_TOK * D * 4);
    float* out3  = (float*)alloc((size_t)T_TOK * D * 4);
    unsigned short* b1h  = (unsigned short*)alloc((size_t)D * D * 2);
    unsigned short* b1l  = (unsigned short*)alloc((size_t)D * D * 2);
    unsigned short* we2h = (unsigned short*)alloc((size_t)E * D * D * 2);
    unsigned short* we2l = (unsigned short*)alloc((size_t)E * D * D * 2);
    unsigned short* we3h = (unsigned short*)alloc((size_t)E * D * D * 2);
    unsigned short* we3l = (unsigned short*)alloc((size_t)E * D * D * 2);
    float* p2    = (float*)alloc((size_t)T_TOK * 4);
    float* p3    = (float*)alloc((size_t)T_TOK * 4);
    int*   l2    = (int*)alloc((size_t)E * T_TOK * 4);
    int*   l3    = (int*)alloc((size_t)E * T_TOK * 4);
    int*   c2    = (int*)alloc(E * 4);
    int*   c3    = (int*)alloc(E * 4);
    float* embed = (float*)alloc(8 * D * 4);
    (void)ws_size; (void)in_sizes; (void)n_in; (void)out_size;

    k_conv_w1<<<dim3(257), dim3(256), 0, stream>>>(W1, b1h, b1l, c2, c3, embed);
    k_prep_we<<<dim3(16, 16, 16), dim3(256), 0, stream>>>(We2, We3, we2h, we2l, we3h, we3l);

    // h = x @ W1^T + b1
    k_gemm_mfma<false><<<dim3(512), dim3(256), 0, stream>>>(
        x, b1h, b1l, b1, nullptr, nullptr, nullptr, h);

    // MoE layer 2
    k_gating<<<dim3(256), dim3(256), 0, stream>>>(h, gw2, p2, l2, c2);
    k_gemm_mfma<true><<<dim3(544), dim3(256), 0, stream>>>(
        h, we2h, we2l, be2, p2, l2, c2, out2);

    // MoE layer 3
    k_gating<<<dim3(256), dim3(256), 0, stream>>>(out2, gw3, p3, l3, c3);
    k_gemm_mfma<true><<<dim3(544), dim3(256), 0, stream>>>(
        out2, we3h, we3l, be3, p3, l3, c3, out3);

    // hidden mean + loss
    k_reduce<<<dim3(8, 64), dim3(256), 0, stream>>>(h, out3, embed);
    k_loss<<<dim3(1), dim3(512), 0, stream>>>(embed, y, out);
}